// Round 9
// baseline (24.940 us; speedup 1.0000x reference)
//
#include <hip/hip_runtime.h>

// Problem constants (fixed by setup_inputs: N=4096, box=50, cutoff=5)
#define N_ATOMS 4096
#define CUTOFF_SQ 25.0f

typedef float f4 __attribute__((ext_vector_type(4)));

// R8: two-phase split to isolate (and hopefully beat) the 64MiB store wall.
// Phase 1: hand-written zero fill, fill-optimal schedule: each block owns a
//   contiguous 16KB chunk; lane-dense dwordx4 stores; no loads, no branches,
//   minimal VGPR -> max store ILP. 4096 blocks x 256 thr.
// Phase 2: compute-only scatter of the ~35k nonzero upper-triangle entries
//   (predicated dword stores). Stream order makes this land after the fill.
// R6's version of this failed only because rocclr's 64MiB memset runs at
// 1.6 TB/s; this replaces it with our own fill.
__global__ __launch_bounds__(256) void zero_fill(float* __restrict__ out) {
    // Block b owns bytes [b*16KB, (b+1)*16KB): 4 dwordx4 per thread.
    f4* p = reinterpret_cast<f4*>(out) + ((size_t)blockIdx.x << 10) + threadIdx.x;
    const f4 z = {0.f, 0.f, 0.f, 0.f};
    p[0]   = z;
    p[256] = z;
    p[512] = z;
    p[768] = z;
}

__global__ __launch_bounds__(256) void pairdist_scatter(
    const float* __restrict__ q,      // [N,3] positions
    const float* __restrict__ cell,   // [3] box lengths
    float* __restrict__ out)          // [N,N] output (pre-zeroed)
{
    const int tid = blockIdx.x * blockDim.x + threadIdx.x;  // 0 .. N*N/4-1
    const int row = tid >> 10;            // 1024 threads per row; wave-uniform
    const int j0  = (tid & 1023) << 2;    // 4 consecutive cols

    // Entire 4-col strip strictly below the diagonal: nothing to write.
    if (j0 + 4 <= row) return;

    const float cx = cell[0], cy = cell[1], cz = cell[2];

    // Row position: wave-uniform address -> scalar loads.
    const float xr = q[3 * row + 0];
    const float yr = q[3 * row + 1];
    const float zr = q[3 * row + 2];

    // Column positions: 4 atoms x 12B = 48B = 3 x float4.
    union { f4 v[3]; float s[12]; } u;
    const f4* q4 = reinterpret_cast<const f4*>(q);
    const int colt = tid & 1023;
#pragma unroll
    for (int m = 0; m < 3; ++m) u.v[m] = q4[3 * colt + m];

#pragma unroll
    for (int k = 0; k < 4; ++k) {
        const int j = j0 + k;
        // min-image |wrapped d| = min(|d|, c-|d|) (bit-exact; absmax==0 R1-R7)
        float dx = fabsf(u.s[3 * k + 0] - xr); dx = fminf(dx, cx - dx);
        float dy = fabsf(u.s[3 * k + 1] - yr); dy = fminf(dy, cy - dy);
        float dz = fabsf(u.s[3 * k + 2] - zr); dz = fminf(dz, cz - dz);
        const float d2 = fmaf(dz, dz, fmaf(dy, dy, dx * dx));
        // j==row gives d2==0 -> excluded; j>row strictly above diagonal.
        const bool keep = (j >= row) & (d2 < CUTOFF_SQ) & (d2 != 0.0f);
        if (keep) out[(size_t)row * N_ATOMS + j] = d2;
    }
}

extern "C" void kernel_launch(void* const* d_in, const int* in_sizes, int n_in,
                              void* d_out, int out_size, void* d_ws, size_t ws_size,
                              hipStream_t stream) {
    const float* q    = (const float*)d_in[0];
    const float* cell = (const float*)d_in[1];
    float* out = (float*)d_out;

    // Phase 1: zero 64 MiB. 4096 blocks x 256 thr, 16KB contiguous per block.
    zero_fill<<<4096, 256, 0, stream>>>(out);

    // Phase 2: scatter nonzero upper-triangle squared distances.
    const int total_threads = (N_ATOMS * N_ATOMS) / 4;
    pairdist_scatter<<<total_threads / 256, 256, 0, stream>>>(q, cell, out);
}

// Round 10
// 17.066 us; speedup vs baseline: 1.4614x; 1.4614x over previous
//
#include <hip/hip_runtime.h>

// Problem constants (fixed by setup_inputs: N=4096, box=50, cutoff=5)
#define N_ATOMS 4096
#define CUTOFF_SQ 25.0f

typedef float f4 __attribute__((ext_vector_type(4)));

// R9 = champion config (R3, 15.9us) + regular-store band split (R4's split
// was only ever tested bundled with nt, which R4/R2 proved harmful).
// - 8-row x 4-col tile/thread: ONE dense float4 store per row; consecutive
//   lanes -> consecutive 16B => 1KB dense wave stores. 2048 blocks x 256.
// - Single dispatch: two-kernel variants (R6/R8) cost ~+9us of dispatch
//   overhead; every dense-store schedule lands 15.9-16.3 => write floor.
// - Regular stores (R4: nt regressed 15.9->18.2 on identical layout).
// - d2!=0 dropped (d2==0 -> reference also writes 0.0; bit-identical).
__global__ __launch_bounds__(256) void pairdist_kernel(
    const float* __restrict__ q,      // [N,3] positions
    const float* __restrict__ cell,   // [3] box lengths
    float* __restrict__ out)          // [N,N] output
{
    const int rowgrp = blockIdx.x >> 2;                      // 0..511
    const int i0 = rowgrp << 3;                              // 8 rows, uniform
    const int colt = ((blockIdx.x & 3) << 8) + threadIdx.x;  // 0..1023
    const int j0 = colt << 2;                                // first col

    float* outp = out + (size_t)i0 * N_ATOMS + j0;

    // Entirely below the diagonal for all 8 rows -> dense zero streaming.
    if (j0 + 4 <= i0) {
        const f4 z = {0.f, 0.f, 0.f, 0.f};
#pragma unroll
        for (int r = 0; r < 8; ++r)
            *reinterpret_cast<f4*>(outp + (size_t)r * N_ATOMS) = z;
        return;
    }

    const float cx = cell[0], cy = cell[1], cz = cell[2];

    // Row positions (block-uniform address -> scalar loads)
    const float* qi = q + 3 * i0;
    float xi[8], yi[8], zi[8];
#pragma unroll
    for (int r = 0; r < 8; ++r) {
        xi[r] = qi[3 * r + 0];
        yi[r] = qi[3 * r + 1];
        zi[r] = qi[3 * r + 2];
    }

    // Column positions: 4 atoms x 12B = 48B = 3 x float4, 16B-aligned.
    union { f4 v[3]; float s[12]; } u;
    const f4* q4 = reinterpret_cast<const f4*>(q);
#pragma unroll
    for (int m = 0; m < 3; ++m) u.v[m] = q4[3 * colt + m];

    if (j0 >= i0 + 8) {
        // Strictly above the diagonal for all 8 rows: no triu predicate.
#pragma unroll
        for (int r = 0; r < 8; ++r) {
            const float xr = xi[r], yr = yi[r], zr = zi[r];
            float res[4];
#pragma unroll
            for (int k = 0; k < 4; ++k) {
                float dx = fabsf(u.s[3 * k + 0] - xr); dx = fminf(dx, cx - dx);
                float dy = fabsf(u.s[3 * k + 1] - yr); dy = fminf(dy, cy - dy);
                float dz = fabsf(u.s[3 * k + 2] - zr); dz = fminf(dz, cz - dz);
                const float d2 = fmaf(dz, dz, fmaf(dy, dy, dx * dx));
                res[k] = (d2 < CUTOFF_SQ) ? d2 : 0.0f;
            }
            f4 v = {res[0], res[1], res[2], res[3]};
            *reinterpret_cast<f4*>(outp + (size_t)r * N_ATOMS) = v;
        }
    } else {
        // Diagonal band (~0.3% of compute threads): full triu predicate.
#pragma unroll
        for (int r = 0; r < 8; ++r) {
            const float xr = xi[r], yr = yi[r], zr = zi[r];
            const int ir = i0 + r;
            float res[4];
#pragma unroll
            for (int k = 0; k < 4; ++k) {
                float dx = fabsf(u.s[3 * k + 0] - xr); dx = fminf(dx, cx - dx);
                float dy = fabsf(u.s[3 * k + 1] - yr); dy = fminf(dy, cy - dy);
                float dz = fabsf(u.s[3 * k + 2] - zr); dz = fminf(dz, cz - dz);
                const float d2 = fmaf(dz, dz, fmaf(dy, dy, dx * dx));
                const bool keep = (d2 < CUTOFF_SQ) & ((j0 + k) >= ir);
                res[k] = keep ? d2 : 0.0f;
            }
            f4 v = {res[0], res[1], res[2], res[3]};
            *reinterpret_cast<f4*>(outp + (size_t)r * N_ATOMS) = v;
        }
    }
}

extern "C" void kernel_launch(void* const* d_in, const int* in_sizes, int n_in,
                              void* d_out, int out_size, void* d_ws, size_t ws_size,
                              hipStream_t stream) {
    const float* q    = (const float*)d_in[0];
    const float* cell = (const float*)d_in[1];
    float* out = (float*)d_out;

    // 512 rowgrps (8 rows each) x 4 col-segment blocks
    pairdist_kernel<<<2048, 256, 0, stream>>>(q, cell, out);
}

// Round 11
// 15.977 us; speedup vs baseline: 1.5610x; 1.0681x over previous
//
#include <hip/hip_runtime.h>

// Problem constants (fixed by setup_inputs: N=4096, box=50, cutoff=5)
#define N_ATOMS 4096
#define CUTOFF_SQ 25.0f

typedef float f4 __attribute__((ext_vector_type(4)));

// FINAL (champion = R3 config, 15.95us best measured).
// Each thread computes an 8-row x 4-col block of the output.
//  - 4 contiguous cols -> ONE dense float4 store per row; consecutive lanes
//    write consecutive 16B chunks => each wave store = dense 1KB span.
//  - column xyz (48B = 3 x float4) loaded once, reused for 8 rows
//  - i0 block-uniform -> row positions scalarize (s_load)
//  - threads entirely below the diagonal stream zeros, no loads/compute
// Session conclusions (measured):
//  * 64 MiB must be rewritten every replay (harness poisons once, never
//    re-poisons) -> write-stream-bound: floor ~= 64MiB/6.5TB/s + dispatch.
//  * All dense single-dispatch schedules: 15.9-17.1us (noise band).
//  * nt stores regress (18.2); two-dispatch fill+scatter regress (24.9-25.4);
//    rocclr's own 64MiB memset runs at only 1.6 TB/s.
//  * d2!=0 dropped: d2==0 -> both reference and kernel write +0.0.
__global__ __launch_bounds__(256) void pairdist_kernel(
    const float* __restrict__ q,      // [N,3] positions
    const float* __restrict__ cell,   // [3] box lengths
    float* __restrict__ out)          // [N,N] output
{
    const int rowgrp = blockIdx.x >> 2;                      // 0..511
    const int i0 = rowgrp << 3;                              // 8 rows/block, uniform
    const int colt = ((blockIdx.x & 3) << 8) + threadIdx.x;  // 0..1023
    const int j0 = colt << 2;                                // first col

    float* outp = out + (size_t)i0 * N_ATOMS + j0;

    // Thread's 4 cols entirely below the diagonal for ALL 8 rows ->
    // pure dense zero streaming.
    if (j0 + 4 <= i0) {
        const f4 z = {0.f, 0.f, 0.f, 0.f};
#pragma unroll
        for (int r = 0; r < 8; ++r)
            *reinterpret_cast<f4*>(outp + (size_t)r * N_ATOMS) = z;
        return;
    }

    const float cx = cell[0], cy = cell[1], cz = cell[2];

    // Row positions (block-uniform address -> scalar loads)
    const float* qi = q + 3 * i0;
    float xi[8], yi[8], zi[8];
#pragma unroll
    for (int r = 0; r < 8; ++r) {
        xi[r] = qi[3 * r + 0];
        yi[r] = qi[3 * r + 1];
        zi[r] = qi[3 * r + 2];
    }

    // Column positions: 4 atoms x 12B = 48B = 3 x float4, 16B-aligned.
    union { f4 v[3]; float s[12]; } u;
    const f4* q4 = reinterpret_cast<const f4*>(q);
#pragma unroll
    for (int m = 0; m < 3; ++m) u.v[m] = q4[3 * colt + m];

#pragma unroll
    for (int r = 0; r < 8; ++r) {
        const float xr = xi[r], yr = yi[r], zr = zi[r];
        const int ir = i0 + r;
        float res[4];
#pragma unroll
        for (int k = 0; k < 4; ++k) {
            // min-image |wrapped d| = min(|d|, c-|d|)  (bit-exact magnitude;
            // absmax == 0 verified every round)
            float dx = fabsf(u.s[3 * k + 0] - xr); dx = fminf(dx, cx - dx);
            float dy = fabsf(u.s[3 * k + 1] - yr); dy = fminf(dy, cy - dy);
            float dz = fabsf(u.s[3 * k + 2] - zr); dz = fminf(dz, cz - dz);
            const float d2 = fmaf(dz, dz, fmaf(dy, dy, dx * dx));
            const bool keep = (d2 < CUTOFF_SQ) & (d2 != 0.0f) & ((j0 + k) >= ir);
            res[k] = keep ? d2 : 0.0f;
        }
        f4 v = {res[0], res[1], res[2], res[3]};
        *reinterpret_cast<f4*>(outp + (size_t)r * N_ATOMS) = v;
    }
}

extern "C" void kernel_launch(void* const* d_in, const int* in_sizes, int n_in,
                              void* d_out, int out_size, void* d_ws, size_t ws_size,
                              hipStream_t stream) {
    const float* q    = (const float*)d_in[0];
    const float* cell = (const float*)d_in[1];
    float* out = (float*)d_out;

    // 512 rowgrps (8 rows each) x 4 col-segment blocks (256 thr x 4 cols = 1024)
    pairdist_kernel<<<2048, 256, 0, stream>>>(q, cell, out);
}